// Round 14
// baseline (197.062 us; speedup 1.0000x reference)
//
#include <hip/hip_runtime.h>
#include <stdint.h>

// Problem: B=8, Lq=Lv=2048, Din=Dout=512, all f32 in/out.
// out[b][l][0:512)=o, [512:1024)=q, [1024:1536)=mv broadcast.
// v14 = r13 with wave roles rebalanced: 2 S-waves (32 rows each, A-fragment
// shared across their 2 i-blocks -> S LDS reads halved) + 4 PV waves
// (unchanged) + 2 C-waves (q/mv copy hidden inside the loop + staging).

typedef __attribute__((ext_vector_type(8))) short short8v;
typedef __attribute__((ext_vector_type(4))) float f32x4;

#define LQ 2048
#define LV 2048
#define DIN 512
#define DOUT 512
#define NB 8
#define KT 32   // KV tile

__device__ __forceinline__ unsigned short f2bf(float x){
    union { float f; unsigned u; } v; v.f = x;
    unsigned r = v.u + 0x7fffu + ((v.u >> 16) & 1u);
    return (unsigned short)(r >> 16);
}

__device__ __forceinline__ void gload16(const void* g, void* l){
    __builtin_amdgcn_global_load_lds((const __attribute__((address_space(1))) void*)g,
                                     (__attribute__((address_space(3))) void*)l, 16, 0, 0);
}

#define SBAR   do{ __builtin_amdgcn_s_barrier(); __builtin_amdgcn_sched_barrier(0); }while(0)
#define LGKM0  do{ asm volatile("s_waitcnt lgkmcnt(0)" ::: "memory"); \
                   __builtin_amdgcn_sched_barrier(0); }while(0)
#define VMCNT4 do{ asm volatile("s_waitcnt vmcnt(4)" ::: "memory"); \
                   __builtin_amdgcn_sched_barrier(0); }while(0)
#define VMCNT0 do{ asm volatile("s_waitcnt vmcnt(0)" ::: "memory"); \
                   __builtin_amdgcn_sched_barrier(0); }while(0)

#define MFMA16(a, bfr, c) __builtin_amdgcn_mfma_f32_16x16x32_bf16(a, bfr, c, 0, 0, 0)

// kernel [DIN][DOUT] f32 -> kT [DOUT][DIN] bf16, scaled by 0.1 (folds the /10)
__global__ void prep_kT(const float* __restrict__ k, unsigned short* __restrict__ kT){
    __shared__ float tile[32][33];
    int tx = threadIdx.x & 31, ty = threadIdx.x >> 5;
    int kb = blockIdx.x, eb = blockIdx.y;
    #pragma unroll
    for (int p = 0; p < 4; ++p){
        int r = ty + p*8;
        tile[r][tx] = k[(size_t)(kb*32 + r)*DOUT + eb*32 + tx];
    }
    __syncthreads();
    #pragma unroll
    for (int p = 0; p < 4; ++p){
        int r = ty + p*8;
        kT[(size_t)(eb*32 + r)*DIN + kb*32 + tx] = f2bf(tile[tx][r] * 0.1f);
    }
}

// v f32 -> v bf16 (natural [b][j][e]) and vT bf16 ([b][e][j]) + masked-max partials
__global__ void prep_v(const float* __restrict__ v, const float* __restrict__ mask,
                       unsigned short* __restrict__ vbf, unsigned short* __restrict__ vT,
                       float* __restrict__ part){
    __shared__ float tile[32][33];
    __shared__ float pmax_l[8][33];
    int tx = threadIdx.x & 31, ty = threadIdx.x >> 5;
    int jb = blockIdx.x, eb = blockIdx.y, b = blockIdx.z;
    const size_t vbase = (size_t)b*LV*DOUT;
    #pragma unroll
    for (int p = 0; p < 4; ++p){
        int r = ty + p*8;
        size_t idx = vbase + (size_t)(jb*32 + r)*DOUT + eb*32 + tx;
        float val = v[idx];
        tile[r][tx] = val;
        vbf[idx] = f2bf(val);
    }
    __syncthreads();
    const size_t tbase = (size_t)b*DOUT*LV;
    #pragma unroll
    for (int p = 0; p < 4; ++p){
        int r = ty + p*8;
        vT[tbase + (size_t)(eb*32 + r)*LV + jb*32 + tx] = f2bf(tile[tx][r]);
    }
    float m = -3e38f;
    #pragma unroll
    for (int k2 = 0; k2 < 4; ++k2){
        int j = ty*4 + k2;
        float msk = mask[b*LV + jb*32 + j];
        m = fmaxf(m, tile[j][tx] - (1.0f - msk)*1e10f);
    }
    pmax_l[ty][tx] = m;
    __syncthreads();
    if (ty == 0){
        float mm = pmax_l[0][tx];
        #pragma unroll
        for (int c = 1; c < 8; ++c) mm = fmaxf(mm, pmax_l[c][tx]);
        part[((size_t)b*64 + jb)*DOUT + eb*32 + tx] = mm;
    }
}

__global__ void mv_final(const float* __restrict__ part, float* __restrict__ mv){
    int b = blockIdx.x; int e = threadIdx.x;
    float m = -3e38f;
    #pragma unroll
    for (int c = 0; c < 64; ++c) m = fmaxf(m, part[((size_t)b*64 + c)*DOUT + e]);
    mv[b*DOUT + e] = m;
}

__global__ __launch_bounds__(512, 1) void flash(const unsigned short* __restrict__ kT,
                                                const unsigned short* __restrict__ vbf,
                                                const unsigned short* __restrict__ vT,
                                                const float* __restrict__ mask,
                                                const float* __restrict__ qf32,
                                                const float* __restrict__ mv,
                                                float* __restrict__ out){
    __shared__ __align__(16) short A_t[2][KT*512];     // main: [j][e] unit^(j&7); prologue: qwL scratch
    __shared__ __align__(16) short T_t[2][512*KT];     // main: [e][j] slot^((e>>1)&3); prologue: kT chunks
    __shared__ __align__(16) float maskL[2048];        // 8KB mask row
    __shared__ short P_lds[2][4][16][40];              // parity x i-block x row x j
    __shared__ float sB[64];

    const int bid = blockIdx.x;
    const int b = bid & 7, qt = bid >> 3;   // batch -> XCD pin
    const int tid = threadIdx.x;
    const int w = tid >> 6, lane = tid & 63;
    const int li = lane & 15, lg = lane >> 4;
    const int i0 = qt*64;

    const unsigned short* vb  = vbf + (size_t)b*LV*DOUT;
    const unsigned short* vTb = vT  + (size_t)b*DOUT*LV;
    const float* mkb = mask + b*LV;

    // staging lambdas: wave w covers A rows w*4..+3, T chunks w*4..+3 (8 waves)
    auto stageA = [&](int j0g, int buf){
        #pragma unroll
        for (int p = 0; p < 4; ++p){
            int j = w*4 + p;
            gload16(vb + (size_t)(j0g + j)*DOUT + ((lane ^ (j&7))*8), &A_t[buf][j*512]);
        }
    };
    auto stageT = [&](int j0g, int buf){
        #pragma unroll
        for (int p = 0; p < 4; ++p){
            int c = w*4 + p;
            int e = c*16 + (lane >> 2);
            gload16(vTb + (size_t)e*LV + j0g + (((lane&3) ^ ((lane>>3)&3))*8),
                    &T_t[buf][c*512]);
        }
    };
    auto stageK = [&](int ch, int buf){
        const unsigned short* kbase = kT + (size_t)ch*32*DIN;
        #pragma unroll
        for (int p = 0; p < 4; ++p){
            int er = w*4 + p;
            gload16(kbase + (size_t)er*DIN + ((lane ^ (er&7))*8),
                    (char*)&T_t[0][0] + buf*32768 + er*1024);
        }
    };

    const bool isS = (w < 2);

    // ======= prologue: fused qw GEMM, 2 passes (one per i-block of 16 rows) =======
    // S-wave w (w=0,1) computes qw for rows i0 + (w*2+ib)*16 + li, ib=0,1.
    short8v qf[2][16];
    const int keyq = li & 7;
    for (int ib = 0; ib < 2; ++ib){
        short8v qb[16];
        if (isS){
            const float* qp = qf32 + (size_t)(b*LQ + i0 + (w*2 + ib)*16 + li)*DIN;
            #pragma unroll
            for (int ks = 0; ks < 16; ++ks){
                float4 lo = *(const float4*)(qp + ks*32 + lg*8);
                float4 hi = *(const float4*)(qp + ks*32 + lg*8 + 4);
                short8v t;
                t[0]=(short)f2bf(lo.x); t[1]=(short)f2bf(lo.y); t[2]=(short)f2bf(lo.z); t[3]=(short)f2bf(lo.w);
                t[4]=(short)f2bf(hi.x); t[5]=(short)f2bf(hi.y); t[6]=(short)f2bf(hi.z); t[7]=(short)f2bf(hi.w);
                qb[ks] = t;
            }
        }
        stageK(0, 0); VMCNT0; SBAR;
        for (int ch = 0; ch < 16; ++ch){
            if (ch + 1 < 16) stageK(ch + 1, (ch + 1) & 1);
            if (isS){
                const short* Kc = (const short*)((char*)&T_t[0][0] + (ch & 1)*32768);
                char* qwL = (char*)&A_t[0][0] + (w*2 + ib)*16384;
                #pragma unroll
                for (int half = 0; half < 2; ++half){
                    const int et = ch*2 + half;
                    const int er = half*16 + li;
                    f32x4 a0 = (f32x4){0.f,0.f,0.f,0.f}, a1 = a0;
                    #pragma unroll
                    for (int ks = 0; ks < 16; ks += 2){
                        short8v f0 = *(const short8v*)&Kc[er*512 + (((ks*4 + lg) ^ keyq)*8)];
                        a0 = MFMA16(f0, qb[ks], a0);
                        short8v f1 = *(const short8v*)&Kc[er*512 + ((((ks+1)*4 + lg) ^ keyq)*8)];
                        a1 = MFMA16(f1, qb[ks+1], a1);
                    }
                    unsigned p0 = (unsigned)f2bf(a0[0] + a1[0]) | ((unsigned)f2bf(a0[1] + a1[1]) << 16);
                    unsigned p1 = (unsigned)f2bf(a0[2] + a1[2]) | ((unsigned)f2bf(a0[3] + a1[3]) << 16);
                    unsigned long long pk = (unsigned long long)p0 | ((unsigned long long)p1 << 32);
                    *(unsigned long long*)(qwL + li*1024 + (((4*et + lg) ^ (keyq << 1))*8)) = pk;
                }
            }
            SBAR; VMCNT0; SBAR;    // reads of cur chunk done; next chunk landed
        }
    }
    if (isS){
        #pragma unroll
        for (int ib = 0; ib < 2; ++ib){
            const char* qwL = (const char*)&A_t[0][0] + (w*2 + ib)*16384;
            #pragma unroll
            for (int ks = 0; ks < 16; ++ks)
                qf[ib][ks] = *(const short8v*)(qwL + li*1024 + (((ks*4 + lg) ^ keyq)*16));
        }
    }
    LGKM0; SBAR;               // P1: qwL reads retired; A_t/T_t free for staging

    // ======= staging prologue =======
    stageA(0, 0); stageA(KT, 1); stageT(0, 0);
    gload16(mkb + w*256 + lane*4, (char*)maskL + w*1024);
    stageT(KT, 1);
    VMCNT4; SBAR;              // P2: buf0 + mask landed; T1's 4 still flying

    if (isS){
        // ============ S role: 32 rows i0 + w*32 .. +32 (2 i-blocks) ============
        float srun0 = 0.0f, srun1 = 0.0f;
        const int key = li & 7;

        auto computeS = [&](int jn){
            const int pn = jn & 1;
            const short* Ac = &A_t[pn][0];
            const int j0 = jn*KT;
            f32x4 mk0 = *(const f32x4*)&maskL[j0 + 4*lg];
            f32x4 mk1 = *(const f32x4*)&maskL[j0 + 16 + 4*lg];

            // acc s<ib><jblk><half>; A-frag read once, used by both i-blocks
            f32x4 s00a = (f32x4){0.f,0.f,0.f,0.f}, s00b = s00a, s01a = s00a, s01b = s00a;
            f32x4 s10a = s00a, s10b = s00a, s11a = s00a, s11b = s00a;
            __builtin_amdgcn_s_setprio(1);
            #pragma unroll
            for (int ks = 0; ks < 8; ++ks){
                short8v a = *(const short8v*)&Ac[li*512 + (((ks*4 + lg)^key)*8)];
                s00a = MFMA16(a, qf[0][ks], s00a);
                s10a = MFMA16(a, qf[1][ks], s10a);
            }
            #pragma unroll
            for (int ks = 8; ks < 16; ++ks){
                short8v a = *(const short8v*)&Ac[li*512 + (((ks*4 + lg)^key)*8)];
                s00b = MFMA16(a, qf[0][ks], s00b);
                s10b = MFMA16(a, qf[1][ks], s10b);
            }
            #pragma unroll
            for (int ks = 0; ks < 8; ++ks){
                short8v a = *(const short8v*)&Ac[(li+16)*512 + (((ks*4 + lg)^key)*8)];
                s01a = MFMA16(a, qf[0][ks], s01a);
                s11a = MFMA16(a, qf[1][ks], s11a);
            }
            #pragma unroll
            for (int ks = 8; ks < 16; ++ks){
                short8v a = *(const short8v*)&Ac[(li+16)*512 + (((ks*4 + lg)^key)*8)];
                s01b = MFMA16(a, qf[0][ks], s01b);
                s11b = MFMA16(a, qf[1][ks], s11b);
            }
            __builtin_amdgcn_s_setprio(0);

            // max-free softmax for both i-blocks (|S| <= ~15; f32-safe)
            float p0[8], p1[8]; float ps0 = 0.f, ps1 = 0.f;
            #pragma unroll
            for (int r = 0; r < 4; ++r){
                float b0 = (mk0[r] - 1.0f)*1e10f;
                float b1 = (mk1[r] - 1.0f)*1e10f;
                p0[r]     = __expf(s00a[r] + s00b[r] + b0);
                p0[4 + r] = __expf(s01a[r] + s01b[r] + b1);
                p1[r]     = __expf(s10a[r] + s10b[r] + b0);
                p1[4 + r] = __expf(s11a[r] + s11b[r] + b1);
            }
            #pragma unroll
            for (int k = 0; k < 8; ++k){ ps0 += p0[k]; ps1 += p1[k]; }
            srun0 += ps0; srun1 += ps1;

            #pragma unroll
            for (int s2 = 0; s2 < 2; ++s2)
                #pragma unroll
                for (int k = 0; k < 2; ++k){
                    unsigned u0 = (unsigned)f2bf(p0[s2*4 + 2*k]) | ((unsigned)f2bf(p0[s2*4 + 2*k + 1]) << 16);
                    *(unsigned*)&P_lds[pn][w*2][li][s2*16 + 4*lg + 2*k] = u0;
                    unsigned u1 = (unsigned)f2bf(p1[s2*4 + 2*k]) | ((unsigned)f2bf(p1[s2*4 + 2*k + 1]) << 16);
                    *(unsigned*)&P_lds[pn][w*2 + 1][li][s2*16 + 4*lg + 2*k] = u1;
                }
        };

        computeS(0);
        LGKM0; SBAR;                        // B0b: P(0) published

        for (int jt = 0; jt < 64; ++jt){
            if (jt + 2 < 64) stageA((jt+2)*KT, jt & 1);
            if (jt < 63) computeS(jt + 1);
            LGKM0; SBAR;                    // B1
            if (jt + 2 < 64){ stageT((jt+2)*KT, jt & 1); VMCNT4; }
            else if (jt == 62){ VMCNT0; }
            SBAR;                           // B2
        }

        srun0 += __shfl_xor(srun0, 16); srun0 += __shfl_xor(srun0, 32);
        srun1 += __shfl_xor(srun1, 16); srun1 += __shfl_xor(srun1, 32);
        if (lg == 0){ sB[(w*2)*16 + li] = srun0; sB[(w*2 + 1)*16 + li] = srun1; }
        LGKM0; SBAR;                        // BE
    } else if (w < 6){
        // ============ PV role: e-quarter [wp*128, +128), all 64 rows ============
        SBAR;                               // B0b
        const int wp = w - 2;
        const int keyT = (li >> 1) & 3;
        f32x4 acc[4][8];
        #pragma unroll
        for (int mt = 0; mt < 4; ++mt)
            #pragma unroll
            for (int nt = 0; nt < 8; ++nt) acc[mt][nt] = (f32x4){0.f,0.f,0.f,0.f};

        for (int jt = 0; jt < 64; ++jt){
            const int pc = jt & 1;
            if (jt + 2 < 64) stageA((jt+2)*KT, jt & 1);

            short8v pa[4];
            #pragma unroll
            for (int mt = 0; mt < 4; ++mt)
                pa[mt] = *(const short8v*)&P_lds[pc][mt][li][lg*8];
            const short* Tc = &T_t[pc][0];
            __builtin_amdgcn_s_setprio(1);
            #pragma unroll
            for (int nt = 0; nt < 8; ++nt){
                int e_local = (wp*8 + nt)*16 + li;
                short8v vf = *(const short8v*)&Tc[e_local*KT + ((lg ^ keyT)*8)];
                #pragma unroll
                for (int mt = 0; mt < 4; ++mt)
                    acc[mt][nt] = MFMA16(pa[mt], vf, acc[mt][nt]);
            }
            __builtin_amdgcn_s_setprio(0);

            SBAR;                           // B1
            if (jt + 2 < 64){ stageT((jt+2)*KT, jt & 1); VMCNT4; }
            else if (jt == 62){ VMCNT0; }
            SBAR;                           // B2
        }

        SBAR;                               // BE: sB published

        #pragma unroll
        for (int mt = 0; mt < 4; ++mt){
            f32x4 s4 = *(const f32x4*)&sB[mt*16 + 4*lg];
            f32x4 inv;
            #pragma unroll
            for (int r = 0; r < 4; ++r) inv[r] = 1.0f / s4[r];
            #pragma unroll
            for (int nt = 0; nt < 8; ++nt)
                #pragma unroll
                for (int r = 0; r < 4; ++r)
                    out[(size_t)(b*LQ + i0 + mt*16 + 4*lg + r)*1536 + wp*128 + nt*16 + li]
                        = acc[mt][nt][r]*inv[r];
        }
    } else {
        // ============ C role: staging + in-loop q/mv copy (row jt per iter) ============
        SBAR;                               // B0b
        const float4* q4  = (const float4*)qf32;
        const float4* mv4 = (const float4*)mv;
        float4* o4 = (float4*)out;

        for (int jt = 0; jt < 64; ++jt){
            if (jt + 2 < 64) stageA((jt+2)*KT, jt & 1);

            {   // copy row jt of this block's q/mv output sections
                size_t grow = (size_t)b*LQ + i0 + jt;
                if (w == 6){
                    float4 v0 = q4[grow*128 + lane];
                    float4 v1 = q4[grow*128 + 64 + lane];
                    o4[grow*384 + 128 + lane]      = v0;
                    o4[grow*384 + 128 + 64 + lane] = v1;
                } else {
                    float4 v0 = mv4[b*128 + lane];
                    float4 v1 = mv4[b*128 + 64 + lane];
                    o4[grow*384 + 256 + lane]      = v0;
                    o4[grow*384 + 256 + 64 + lane] = v1;
                }
            }

            SBAR;                           // B1
            if (jt + 2 < 64){ stageT((jt+2)*KT, jt & 1); VMCNT4; }
            else if (jt == 62){ VMCNT0; }
            SBAR;                           // B2
        }

        SBAR;                               // BE
    }
}

extern "C" void kernel_launch(void* const* d_in, const int* in_sizes, int n_in,
                              void* d_out, int out_size, void* d_ws, size_t ws_size,
                              hipStream_t stream){
    const float* q     = (const float*)d_in[0];
    const float* v     = (const float*)d_in[1];
    const float* vmask = (const float*)d_in[2];
    const float* kern  = (const float*)d_in[3];
    float* out = (float*)d_out;
    char* ws = (char*)d_ws;

    const size_t SZ_QW = (size_t)NB*LQ*DOUT*2;       // 16 MB (layout kept)
    unsigned short* vbf = (unsigned short*)(ws + SZ_QW);
    unsigned short* vT  = (unsigned short*)(ws + 2*SZ_QW);
    unsigned short* kT  = (unsigned short*)(ws + 3*SZ_QW);
    float* mv   = (float*)(ws + 3*SZ_QW + 524288);
    float* part = (float*)(ws + 3*SZ_QW + 524288 + 16384);

    hipLaunchKernelGGL(prep_kT,  dim3(16,16),   dim3(256), 0, stream, kern, kT);
    hipLaunchKernelGGL(prep_v,   dim3(64,16,8), dim3(256), 0, stream, v, vmask, vbf, vT, part);
    hipLaunchKernelGGL(mv_final, dim3(8),       dim3(512), 0, stream, part, mv);
    hipLaunchKernelGGL(flash,    dim3(256),     dim3(512), 0, stream, kT, vbf, vT, vmask, q, mv, out);
}